// Round 1
// baseline (299.138 us; speedup 1.0000x reference)
//
#include <hip/hip_runtime.h>
#include <hip/hip_bf16.h>
#include <cstddef>

// Problem dims (fixed by setup_inputs): B=8, T=200, U=50, U1=51, H=320, V=1024.
#define Bdim 8
#define Tdim 200
#define Udim 50
#define U1dim 51
#define Hdim 320
#define Vdim 1024
#define NEGV -1.0e30f

// ---------------------------------------------------------------------------
// Generic tiled f32 GEMM with optional bias: C[m][n] = sum_k A[m][k]*B[k][n] + bias[n]
// 64x64 tile, BK=16, 256 threads, 4x4 micro-tile per thread.
// ---------------------------------------------------------------------------
__global__ __launch_bounds__(256) void gemm_bias(
    const float* __restrict__ A, const float* __restrict__ B,
    const float* __restrict__ bias, float* __restrict__ C,
    int M, int N, int K)
{
    __shared__ float As[16][68];  // As[k][m], padded stride 68 (16B-aligned, conflict-light)
    __shared__ float Bs[16][68];  // Bs[k][n]
    const int tid = threadIdx.x;
    const int tx = tid & 15;        // n-direction (0..15)
    const int ty = tid >> 4;        // m-direction (0..15)
    const int m0 = blockIdx.y * 64;
    const int n0 = blockIdx.x * 64;

    const int rA = tid >> 2;          // 0..63 (m within tile)
    const int cA = (tid & 3) * 4;     // 0,4,8,12 (k within tile)
    const int kr = tid >> 4;          // 0..15 (k within tile)
    const int cB = (tid & 15) * 4;    // 0..60 (n within tile)

    float acc[4][4] = {};

    for (int k0 = 0; k0 < K; k0 += 16) {
        float4 av = make_float4(0.f, 0.f, 0.f, 0.f);
        if (m0 + rA < M)
            av = *(const float4*)&A[(size_t)(m0 + rA) * K + k0 + cA];
        As[cA + 0][rA] = av.x;
        As[cA + 1][rA] = av.y;
        As[cA + 2][rA] = av.z;
        As[cA + 3][rA] = av.w;
        *(float4*)&Bs[kr][cB] = *(const float4*)&B[(size_t)(k0 + kr) * N + n0 + cB];
        __syncthreads();
        #pragma unroll
        for (int k = 0; k < 16; ++k) {
            float4 a = *(const float4*)&As[k][ty * 4];
            float4 b = *(const float4*)&Bs[k][tx * 4];
            acc[0][0] += a.x * b.x; acc[0][1] += a.x * b.y; acc[0][2] += a.x * b.z; acc[0][3] += a.x * b.w;
            acc[1][0] += a.y * b.x; acc[1][1] += a.y * b.y; acc[1][2] += a.y * b.z; acc[1][3] += a.y * b.w;
            acc[2][0] += a.z * b.x; acc[2][1] += a.z * b.y; acc[2][2] += a.z * b.z; acc[2][3] += a.z * b.w;
            acc[3][0] += a.w * b.x; acc[3][1] += a.w * b.y; acc[3][2] += a.w * b.z; acc[3][3] += a.w * b.w;
        }
        __syncthreads();
    }

    float4 bv = make_float4(0.f, 0.f, 0.f, 0.f);
    if (bias) bv = *(const float4*)&bias[n0 + tx * 4];
    #pragma unroll
    for (int i = 0; i < 4; ++i) {
        int row = m0 + ty * 4 + i;
        if (row < M) {
            float4 o;
            o.x = acc[i][0] + bv.x;
            o.y = acc[i][1] + bv.y;
            o.z = acc[i][2] + bv.z;
            o.w = acc[i][3] + bv.w;
            *(float4*)&C[(size_t)row * N + n0 + tx * 4] = o;
        }
    }
}

// ---------------------------------------------------------------------------
// Joint + fused log-softmax stats.
// Block = (b,t). Writes logits row (51*1024 floats) to out+1, and
// lp_blank[b,t,u], lp_label[b,t,u] to workspace.
// Each of 4 waves owns u = wave, wave+4, ...  Lane-layout: v = k*64 + lane.
// ---------------------------------------------------------------------------
__global__ __launch_bounds__(256) void joint_lse(
    const float* __restrict__ enc_part, const float* __restrict__ pred_part,
    const int* __restrict__ ys, float* __restrict__ out,
    float* __restrict__ lp_blank, float* __restrict__ lp_label)
{
    const int bt = blockIdx.x;       // b*T + t
    const int b = bt / Tdim;
    const int tid = threadIdx.x;
    __shared__ float E[Vdim];
    *(float4*)&E[tid * 4] = *(const float4*)&enc_part[(size_t)bt * Vdim + tid * 4];
    __syncthreads();

    const int lane = tid & 63;
    const int wave = tid >> 6;
    float* logits = out + 1;  // element 0 of d_out is the loss scalar

    for (int u = wave; u < U1dim; u += 4) {
        const float* P = pred_part + (size_t)(b * U1dim + u) * Vdim;
        float* Lrow = logits + ((size_t)bt * U1dim + u) * Vdim;
        float l[16];
        float m = -3.0e38f;
        #pragma unroll
        for (int k = 0; k < 16; ++k) {
            int v = k * 64 + lane;
            float x = E[v] + P[v];
            l[k] = x;
            Lrow[v] = x;        // scalar store (base is off-by-1-float aligned)
            m = fmaxf(m, x);
        }
        #pragma unroll
        for (int off = 32; off >= 1; off >>= 1) m = fmaxf(m, __shfl_xor(m, off));
        float s = 0.f;
        #pragma unroll
        for (int k = 0; k < 16; ++k) s += __expf(l[k] - m);
        #pragma unroll
        for (int off = 32; off >= 1; off >>= 1) s += __shfl_xor(s, off);
        float lse = m + __logf(s);

        int vlab = (u < Udim) ? ys[b * Udim + u] : 0;
        int ksel = vlab >> 6;
        int lsel = vlab & 63;
        float cand = 0.f;
        #pragma unroll
        for (int k = 0; k < 16; ++k) if (k == ksel) cand = l[k];
        float lab = __shfl(cand, lsel);
        float l0 = __shfl(l[0], 0);

        if (lane == 0) {
            lp_blank[(size_t)bt * U1dim + u] = l0 - lse;
            if (u < Udim) lp_label[(size_t)bt * Udim + u] = lab - lse;
        }
    }
}

// ---------------------------------------------------------------------------
// RNN-T alpha recursion, wavefront over anti-diagonals d = t+u.
// One block per batch element; lp arrays staged in LDS transposed to [u][t]
// (per-lane stride 199 elements -> bank-conflict-free diagonal reads).
// alpha[t][u] = logaddexp(alpha[t-1][u] + lp_blank[t-1][u],
//                         alpha[t][u-1] + lp_label[t][u-1])
// with alpha[0][0] = 0 (row 0 then reduces to the cumsum of the reference).
// ---------------------------------------------------------------------------
__global__ __launch_bounds__(256) void alpha_kernel(
    const float* __restrict__ lp_blank, const float* __restrict__ lp_label,
    const int* __restrict__ ylen, float* __restrict__ loss_part)
{
    __shared__ float s_bl[U1dim * Tdim];   // [u][t]  40.8 KB
    __shared__ float s_lab[Udim * Tdim];   // [u][t]  40.0 KB
    const int b = blockIdx.x;
    const int tid = threadIdx.x;
    const float* gb = lp_blank + (size_t)b * Tdim * U1dim;
    const float* gl = lp_label + (size_t)b * Tdim * Udim;
    for (int i = tid; i < Tdim * U1dim; i += 256) {
        int t = i / U1dim, u = i % U1dim;
        s_bl[u * Tdim + t] = gb[i];
    }
    for (int i = tid; i < Tdim * Udim; i += 256) {
        int t = i / Udim, u = i % Udim;
        s_lab[u * Tdim + t] = gl[i];
    }
    __syncthreads();

    if (tid < 64) {
        const int u = tid;
        float cur = NEGV;
        for (int d = 0; d < Tdim + U1dim - 1; ++d) {
            float left = __shfl_up(cur, 1);   // alpha[t][u-1] from diagonal d-1
            int t = d - u;
            if (u < U1dim && t >= 0 && t < Tdim) {
                float h = (t >= 1) ? cur + s_bl[u * Tdim + (t - 1)] : NEGV;
                float g = (u >= 1) ? left + s_lab[(u - 1) * Tdim + t] : NEGV;
                float mx = fmaxf(h, g);
                float nv = mx + log1pf(__expf(-fabsf(h - g)));
                if (d == 0) nv = 0.f;         // base case alpha[0][0] = 0
                cur = nv;
            }
        }
        const int L = ylen[b];
        if (u == L) loss_part[b] = -(cur + s_bl[L * Tdim + (Tdim - 1)]);
    }
}

__global__ void loss_mean(const float* __restrict__ loss_part, float* __restrict__ out)
{
    if (threadIdx.x == 0) {
        float s = 0.f;
        for (int i = 0; i < Bdim; ++i) s += loss_part[i];
        out[0] = s * (1.0f / Bdim);
    }
}

// ---------------------------------------------------------------------------
extern "C" void kernel_launch(void* const* d_in, const int* in_sizes, int n_in,
                              void* d_out, int out_size, void* d_ws, size_t ws_size,
                              hipStream_t stream)
{
    const float* enc      = (const float*)d_in[0];   // (8,200,320)
    const float* pred     = (const float*)d_in[1];   // (8,51,320)
    const int*   ys       = (const int*)d_in[4];     // (8,50)
    const int*   ylen     = (const int*)d_in[5];     // (8,)
    const float* W_enc    = (const float*)d_in[6];   // (320,320)
    const float* b_enc    = (const float*)d_in[7];   // (320,)
    const float* W_pred   = (const float*)d_in[8];
    const float* b_pred   = (const float*)d_in[9];
    const float* W_ff_enc = (const float*)d_in[10];  // (320,1024)
    const float* W_ff_pred= (const float*)d_in[11];
    const float* b_ff     = (const float*)d_in[12];  // (1024,)
    float* out = (float*)d_out;
    float* ws  = (float*)d_ws;

    // workspace layout (floats)
    float* enc_proj  = ws;              // 1600*320  = 512000
    float* pred_proj = ws + 512000;     // 408*320   = 130560
    float* enc_part  = ws + 642560;     // 1600*1024 = 1638400
    float* pred_part = ws + 2280960;    // 408*1024  = 417792
    float* lp_blank  = ws + 2698752;    // 8*200*51  = 81600
    float* lp_label  = ws + 2780352;    // 8*200*50  = 80000
    float* loss_part = ws + 2860352;    // 8

    dim3 blk(256);
    // enc_proj = enc @ W_enc + b_enc              (1600 x 320, K=320)
    gemm_bias<<<dim3(5, 25), blk, 0, stream>>>(enc, W_enc, b_enc, enc_proj, Bdim * Tdim, Hdim, Hdim);
    // pred_proj = pred @ W_pred + b_pred          (408 x 320, K=320)
    gemm_bias<<<dim3(5, 7), blk, 0, stream>>>(pred, W_pred, b_pred, pred_proj, Bdim * U1dim, Hdim, Hdim);
    // enc_part = enc_proj @ W_ff_enc              (1600 x 1024, K=320)
    gemm_bias<<<dim3(16, 25), blk, 0, stream>>>(enc_proj, W_ff_enc, nullptr, enc_part, Bdim * Tdim, Vdim, Hdim);
    // pred_part = pred_proj @ W_ff_pred + b_ff    (408 x 1024, K=320)
    gemm_bias<<<dim3(16, 7), blk, 0, stream>>>(pred_proj, W_ff_pred, b_ff, pred_part, Bdim * U1dim, Vdim, Hdim);
    // logits + log-softmax stats
    joint_lse<<<dim3(Bdim * Tdim), blk, 0, stream>>>(enc_part, pred_part, ys, out, lp_blank, lp_label);
    // alpha wavefront + per-batch loss
    alpha_kernel<<<dim3(Bdim), blk, 0, stream>>>(lp_blank, lp_label, ylen, loss_part);
    // mean
    loss_mean<<<dim3(1), dim3(64), 0, stream>>>(loss_part, out);
}

// Round 2
// 243.909 us; speedup vs baseline: 1.2264x; 1.2264x over previous
//
#include <hip/hip_runtime.h>
#include <hip/hip_bf16.h>
#include <cstddef>

// Problem dims (fixed by setup_inputs): B=8, T=200, U=50, U1=51, H=320, V=1024.
#define Bdim 8
#define Tdim 200
#define Udim 50
#define U1dim 51
#define Hdim 320
#define Vdim 1024
#define NEGV -1.0e30f

using short8 = __attribute__((ext_vector_type(8))) short;
using f32x4  = __attribute__((ext_vector_type(4))) float;

static __device__ __forceinline__ ushort f2bf(float x) {
    __hip_bfloat16 h = __float2bfloat16(x);
    return *reinterpret_cast<ushort*>(&h);
}

// ---------------------------------------------------------------------------
// f32 -> bf16 elementwise convert (x4 vectorized)
// ---------------------------------------------------------------------------
__global__ __launch_bounds__(256) void cvt_bf16(
    const float* __restrict__ in, ushort* __restrict__ out, int n4)
{
    int i = blockIdx.x * 256 + threadIdx.x;
    if (i >= n4) return;
    float4 v = ((const float4*)in)[i];
    ushort4 o;
    o.x = f2bf(v.x); o.y = f2bf(v.y); o.z = f2bf(v.z); o.w = f2bf(v.w);
    ((ushort4*)out)[i] = o;
}

// ---------------------------------------------------------------------------
// W (K x N, f32, row-major) -> Wt (N x K, bf16, row-major). 32x32 LDS tiles.
// ---------------------------------------------------------------------------
__global__ __launch_bounds__(256) void transpose_cvt(
    const float* __restrict__ W, ushort* __restrict__ Wt, int K, int N)
{
    __shared__ float tile[32][33];
    const int tx = threadIdx.x & 31, ty = threadIdx.x >> 5;
    const int n0 = blockIdx.x * 32, k0 = blockIdx.y * 32;
    #pragma unroll
    for (int i = 0; i < 4; ++i)
        tile[ty + i * 8][tx] = W[(size_t)(k0 + ty + i * 8) * N + n0 + tx];
    __syncthreads();
    #pragma unroll
    for (int i = 0; i < 4; ++i)
        Wt[(size_t)(n0 + ty + i * 8) * K + k0 + tx] = f2bf(tile[tx][ty + i * 8]);
}

// ---------------------------------------------------------------------------
// bf16 MFMA GEMM: C[m][n] = sum_k A[m][k] * Bt[n][k] + bias[n]
// A: (M x K) bf16 row-major; Bt: (N x K) bf16 row-major (pre-transposed).
// 64x64 tile, BK=32, 256 threads = 4 waves, each wave a 32x32 sub-tile
// (2x2 fragments of mfma_f32_16x16x32_bf16). K, N multiples of 32/64; M guarded.
// ---------------------------------------------------------------------------
template <bool OUT_BF16>
__global__ __launch_bounds__(256) void gemm_mfma(
    const ushort* __restrict__ A, const ushort* __restrict__ Bt,
    const float* __restrict__ bias, void* __restrict__ Cout,
    int M, int N, int K)
{
    __shared__ short As[64][40];  // row stride 80 B (16B-aligned, 2-way bank alias = free)
    __shared__ short Bs[64][40];
    const int tid = threadIdx.x;
    const int m0 = blockIdx.y * 64;
    const int n0 = blockIdx.x * 64;

    const int srow = tid >> 2;          // 0..63
    const int skc  = (tid & 3) * 8;     // 0,8,16,24

    const int lane = tid & 63;
    const int wave = tid >> 6;
    const int wr = wave >> 1, wc = wave & 1;
    const int lrow = lane & 15;
    const int kg = (lane >> 4) * 8;

    f32x4 acc[2][2] = {};

    for (int k0 = 0; k0 < K; k0 += 32) {
        int4 av = make_int4(0, 0, 0, 0);
        if (m0 + srow < M)
            av = *(const int4*)&A[(size_t)(m0 + srow) * K + k0 + skc];
        *(int4*)&As[srow][skc] = av;
        int4 bv = *(const int4*)&Bt[(size_t)(n0 + srow) * K + k0 + skc];
        *(int4*)&Bs[srow][skc] = bv;
        __syncthreads();

        short8 a0 = *(const short8*)&As[wr * 32 + lrow][kg];
        short8 a1 = *(const short8*)&As[wr * 32 + 16 + lrow][kg];
        short8 b0 = *(const short8*)&Bs[wc * 32 + lrow][kg];
        short8 b1 = *(const short8*)&Bs[wc * 32 + 16 + lrow][kg];
        acc[0][0] = __builtin_amdgcn_mfma_f32_16x16x32_bf16(a0, b0, acc[0][0], 0, 0, 0);
        acc[0][1] = __builtin_amdgcn_mfma_f32_16x16x32_bf16(a0, b1, acc[0][1], 0, 0, 0);
        acc[1][0] = __builtin_amdgcn_mfma_f32_16x16x32_bf16(a1, b0, acc[1][0], 0, 0, 0);
        acc[1][1] = __builtin_amdgcn_mfma_f32_16x16x32_bf16(a1, b1, acc[1][1], 0, 0, 0);
        __syncthreads();
    }

    // C/D layout (verified m89): col = lane&15, row = (lane>>4)*4 + reg
    #pragma unroll
    for (int fm = 0; fm < 2; ++fm) {
        #pragma unroll
        for (int fn = 0; fn < 2; ++fn) {
            int col = n0 + wc * 32 + fn * 16 + lrow;
            int r0 = m0 + wr * 32 + fm * 16 + (lane >> 4) * 4;
            float bv = bias ? bias[col] : 0.f;
            #pragma unroll
            for (int r = 0; r < 4; ++r) {
                int row = r0 + r;
                if (row < M) {
                    float val = acc[fm][fn][r] + bv;
                    if (OUT_BF16)
                        ((ushort*)Cout)[(size_t)row * N + col] = f2bf(val);
                    else
                        ((float*)Cout)[(size_t)row * N + col] = val;
                }
            }
        }
    }
}

// ---------------------------------------------------------------------------
// Joint + fused log-softmax stats.
// Block = (b,t). Writes logits row (51*1024 floats) to out+1, and
// lp_blank[b,t,u], lp_label[b,t,u] to workspace.
// ---------------------------------------------------------------------------
__global__ __launch_bounds__(256) void joint_lse(
    const float* __restrict__ enc_part, const float* __restrict__ pred_part,
    const int* __restrict__ ys, float* __restrict__ out,
    float* __restrict__ lp_blank, float* __restrict__ lp_label)
{
    const int bt = blockIdx.x;       // b*T + t
    const int b = bt / Tdim;
    const int tid = threadIdx.x;
    __shared__ float E[Vdim];
    *(float4*)&E[tid * 4] = *(const float4*)&enc_part[(size_t)bt * Vdim + tid * 4];
    __syncthreads();

    const int lane = tid & 63;
    const int wave = tid >> 6;
    float* logits = out + 1;  // element 0 of d_out is the loss scalar

    for (int u = wave; u < U1dim; u += 4) {
        const float* P = pred_part + (size_t)(b * U1dim + u) * Vdim;
        float* Lrow = logits + ((size_t)bt * U1dim + u) * Vdim;
        float l[16];
        float m = -3.0e38f;
        #pragma unroll
        for (int k = 0; k < 16; ++k) {
            int v = k * 64 + lane;
            float x = E[v] + P[v];
            l[k] = x;
            Lrow[v] = x;
            m = fmaxf(m, x);
        }
        #pragma unroll
        for (int off = 32; off >= 1; off >>= 1) m = fmaxf(m, __shfl_xor(m, off));
        float s = 0.f;
        #pragma unroll
        for (int k = 0; k < 16; ++k) s += __expf(l[k] - m);
        #pragma unroll
        for (int off = 32; off >= 1; off >>= 1) s += __shfl_xor(s, off);
        float lse = m + __logf(s);

        int vlab = (u < Udim) ? ys[b * Udim + u] : 0;
        int ksel = vlab >> 6;
        int lsel = vlab & 63;
        float cand = 0.f;
        #pragma unroll
        for (int k = 0; k < 16; ++k) if (k == ksel) cand = l[k];
        float lab = __shfl(cand, lsel);
        float l0 = __shfl(l[0], 0);

        if (lane == 0) {
            lp_blank[(size_t)bt * U1dim + u] = l0 - lse;
            if (u < Udim) lp_label[(size_t)bt * Udim + u] = lab - lse;
        }
    }
}

// ---------------------------------------------------------------------------
// RNN-T alpha recursion, wavefront over anti-diagonals d = t+u.
// ---------------------------------------------------------------------------
__global__ __launch_bounds__(256) void alpha_kernel(
    const float* __restrict__ lp_blank, const float* __restrict__ lp_label,
    const int* __restrict__ ylen, float* __restrict__ loss_part)
{
    __shared__ float s_bl[U1dim * Tdim];   // [u][t]
    __shared__ float s_lab[Udim * Tdim];   // [u][t]
    const int b = blockIdx.x;
    const int tid = threadIdx.x;
    const float* gb = lp_blank + (size_t)b * Tdim * U1dim;
    const float* gl = lp_label + (size_t)b * Tdim * Udim;
    for (int i = tid; i < Tdim * U1dim; i += 256) {
        int t = i / U1dim, u = i % U1dim;
        s_bl[u * Tdim + t] = gb[i];
    }
    for (int i = tid; i < Tdim * Udim; i += 256) {
        int t = i / Udim, u = i % Udim;
        s_lab[u * Tdim + t] = gl[i];
    }
    __syncthreads();

    if (tid < 64) {
        const int u = tid;
        float cur = NEGV;
        for (int d = 0; d < Tdim + U1dim - 1; ++d) {
            float left = __shfl_up(cur, 1);
            int t = d - u;
            if (u < U1dim && t >= 0 && t < Tdim) {
                float h = (t >= 1) ? cur + s_bl[u * Tdim + (t - 1)] : NEGV;
                float g = (u >= 1) ? left + s_lab[(u - 1) * Tdim + t] : NEGV;
                float mx = fmaxf(h, g);
                float nv = mx + log1pf(__expf(-fabsf(h - g)));
                if (d == 0) nv = 0.f;
                cur = nv;
            }
        }
        const int L = ylen[b];
        if (u == L) loss_part[b] = -(cur + s_bl[L * Tdim + (Tdim - 1)]);
    }
}

__global__ void loss_mean(const float* __restrict__ loss_part, float* __restrict__ out)
{
    if (threadIdx.x == 0) {
        float s = 0.f;
        for (int i = 0; i < Bdim; ++i) s += loss_part[i];
        out[0] = s * (1.0f / Bdim);
    }
}

// ---------------------------------------------------------------------------
extern "C" void kernel_launch(void* const* d_in, const int* in_sizes, int n_in,
                              void* d_out, int out_size, void* d_ws, size_t ws_size,
                              hipStream_t stream)
{
    const float* enc      = (const float*)d_in[0];   // (8,200,320)
    const float* pred     = (const float*)d_in[1];   // (8,51,320)
    const int*   ys       = (const int*)d_in[4];     // (8,50)
    const int*   ylen     = (const int*)d_in[5];     // (8,)
    const float* W_enc    = (const float*)d_in[6];   // (320,320)
    const float* b_enc    = (const float*)d_in[7];   // (320,)
    const float* W_pred   = (const float*)d_in[8];
    const float* b_pred   = (const float*)d_in[9];
    const float* W_ff_enc = (const float*)d_in[10];  // (320,1024)
    const float* W_ff_pred= (const float*)d_in[11];
    const float* b_ff     = (const float*)d_in[12];  // (1024,)
    float* out = (float*)d_out;
    char* ws = (char*)d_ws;

    // -------- workspace layout (byte offsets, 16B-aligned) --------
    // Region 0..6.55MB: first holds enc_bf + pred_bf, later overwritten by enc_part f32
    ushort* enc_bf       = (ushort*)(ws + 0);           // 512000 bf16 = 1,024,000 B
    ushort* pred_bf      = (ushort*)(ws + 1024000);     // 130560 bf16 =   261,120 B
    float*  enc_part     = (float*) (ws + 0);           // 1,638,400 f32 = 6,553,600 B (after GEMM1/2)
    float*  pred_part    = (float*) (ws + 6553600);     //   417,792 f32 = 1,671,168 B
    float*  lp_blank     = (float*) (ws + 8224768);     //    81,600 f32
    float*  lp_label     = (float*) (ws + 8551168);     //    80,000 f32
    float*  loss_part    = (float*) (ws + 8871168);     //         8 f32
    ushort* Wenc_t       = (ushort*)(ws + 8871200);     // 102,400 bf16
    ushort* Wpred_t      = (ushort*)(ws + 9076000);     // 102,400 bf16
    ushort* Wffe_t       = (ushort*)(ws + 9280800);     // 327,680 bf16
    ushort* Wffp_t       = (ushort*)(ws + 9936160);     // 327,680 bf16
    ushort* enc_proj_bf  = (ushort*)(ws + 10591520);    // 512,000 bf16
    ushort* pred_proj_bf = (ushort*)(ws + 11615520);    // 130,560 bf16  (ends 11,876,640)

    dim3 blk(256);

    // converts
    cvt_bf16<<<dim3(500), blk, 0, stream>>>(enc, enc_bf, 128000);
    cvt_bf16<<<dim3(128), blk, 0, stream>>>(pred, pred_bf, 32640);
    // weight transposes (K x N -> N x K bf16)
    transpose_cvt<<<dim3(10, 10), blk, 0, stream>>>(W_enc,     Wenc_t, Hdim, Hdim);
    transpose_cvt<<<dim3(10, 10), blk, 0, stream>>>(W_pred,    Wpred_t, Hdim, Hdim);
    transpose_cvt<<<dim3(32, 10), blk, 0, stream>>>(W_ff_enc,  Wffe_t, Hdim, Vdim);
    transpose_cvt<<<dim3(32, 10), blk, 0, stream>>>(W_ff_pred, Wffp_t, Hdim, Vdim);

    // GEMM1: enc_proj = enc @ W_enc + b_enc  -> bf16 (1600 x 320, K=320)
    gemm_mfma<true><<<dim3(5, 25), blk, 0, stream>>>(enc_bf, Wenc_t, b_enc, enc_proj_bf, Bdim * Tdim, Hdim, Hdim);
    // GEMM2: pred_proj = pred @ W_pred + b_pred -> bf16 (408 x 320)
    gemm_mfma<true><<<dim3(5, 7), blk, 0, stream>>>(pred_bf, Wpred_t, b_pred, pred_proj_bf, Bdim * U1dim, Hdim, Hdim);
    // GEMM3: enc_part = enc_proj @ W_ff_enc -> f32 (1600 x 1024)  [overwrites enc_bf/pred_bf region]
    gemm_mfma<false><<<dim3(16, 25), blk, 0, stream>>>(enc_proj_bf, Wffe_t, nullptr, enc_part, Bdim * Tdim, Vdim, Hdim);
    // GEMM4: pred_part = pred_proj @ W_ff_pred + b_ff -> f32 (408 x 1024)
    gemm_mfma<false><<<dim3(16, 7), blk, 0, stream>>>(pred_proj_bf, Wffp_t, b_ff, pred_part, Bdim * U1dim, Vdim, Hdim);

    // logits + log-softmax stats
    joint_lse<<<dim3(Bdim * Tdim), blk, 0, stream>>>(enc_part, pred_part, ys, out, lp_blank, lp_label);
    // alpha wavefront + per-batch loss
    alpha_kernel<<<dim3(Bdim), blk, 0, stream>>>(lp_blank, lp_label, ylen, loss_part);
    // mean
    loss_mean<<<dim3(1), dim3(64), 0, stream>>>(loss_part, out);
}